// Round 4
// baseline (117.908 us; speedup 1.0000x reference)
//
#include <hip/hip_runtime.h>
#include <math.h>

typedef _Float16 half8   __attribute__((ext_vector_type(8)));
typedef _Float16 half4v  __attribute__((ext_vector_type(4)));
typedef float    float4v __attribute__((ext_vector_type(4)));

#define BM    64
#define KDIM  256
#define HSW   65    // fp32 h-tile stride: (r+k)%32 -> 2-way (free)

// ---- pre-kernel: W1 fp32 -> fp16 into d_ws (64x256 = 32 KB, L1-resident) ----
__global__ void w1_cvt(const float* __restrict__ W1, _Float16* __restrict__ w1h)
{
    int i = (blockIdx.x * 256 + threadIdx.x) * 4;   // 16 blocks x 256 thr x 4 elems
    float4v v = *(const float4v*)(W1 + i);
    half4v h;
    h[0] = (_Float16)v[0]; h[1] = (_Float16)v[1];
    h[2] = (_Float16)v[2]; h[3] = (_Float16)v[3];
    *(half4v*)(w1h + i) = h;
}

__global__ __launch_bounds__(256, 4)
void qc_fused(const float* __restrict__ x,
              const _Float16* __restrict__ w1h,
              const float* __restrict__ b1,
              const float* __restrict__ W2,
              const float* __restrict__ b2,
              const float* __restrict__ qw,
              float* __restrict__ out)
{
    __shared__ float hs[BM * HSW];    // 16640 B
    __shared__ float angs[BM * 4];
    __shared__ float trig[32];        // [layer][qubit][{cy,sy,cz,sz}] — wave0 only

    const int tid  = threadIdx.x;
    const int lane = tid & 63;
    const int wv   = tid >> 6;        // wave -> rows wv*16 .. wv*16+15
    const int m    = lane & 15;
    const int q    = lane >> 4;
    const int row0 = blockIdx.x * BM;

    // trig: written AND read only by wave 0 (no barrier needed for it)
    if (tid < 8) {
        int l = tid >> 2, i = tid & 3;
        float wy = qw[(l * 4 + i) * 2 + 0];
        float wz = qw[(l * 4 + i) * 2 + 1];
        float sy, cy, sz, cz;
        sincosf(0.5f * wy, &sy, &cy);
        sincosf(0.5f * wz, &sz, &cz);
        trig[(l * 4 + i) * 4 + 0] = cy;
        trig[(l * 4 + i) * 4 + 1] = sy;
        trig[(l * 4 + i) * 4 + 2] = cz;
        trig[(l * 4 + i) * 4 + 3] = sz;
    }

    // ---- A-fragments: x direct global -> fp16 regs, chunked (low pressure) ----
    // A[m][k = q*8 + j]; frag f covers k = f*32 + q*8 .. +7
    const float* xrow = x + (size_t)(row0 + wv * 16 + m) * KDIM + q * 8;
    half8 afr[8];
    #pragma unroll
    for (int f = 0; f < 8; ++f) {
        float4v v0 = *(const float4v*)(xrow + f * 32);
        float4v v1 = *(const float4v*)(xrow + f * 32 + 4);
        afr[f][0] = (_Float16)v0[0]; afr[f][1] = (_Float16)v0[1];
        afr[f][2] = (_Float16)v0[2]; afr[f][3] = (_Float16)v0[3];
        afr[f][4] = (_Float16)v1[0]; afr[f][5] = (_Float16)v1[1];
        afr[f][6] = (_Float16)v1[2]; afr[f][7] = (_Float16)v1[3];
    }

    // b1 per-lane values for the epilogue (tiny, L1-hit)
    float b1v[4];
    #pragma unroll
    for (int b = 0; b < 4; ++b) b1v[b] = b1[16 * b + m];

    // ---- MFMA: B-fragments straight from global fp16 W1 (L1-resident) ----
    float4v acc[4] = {};
    #pragma unroll
    for (int f = 0; f < 8; ++f) {
        const int ko = f * 32 + q * 8;
        #pragma unroll
        for (int b = 0; b < 4; ++b) {
            half8 bf = *(const half8*)(w1h + (size_t)(16 * b + m) * KDIM + ko);
            acc[b] = __builtin_amdgcn_mfma_f32_16x16x32_f16(afr[f], bf, acc[b], 0, 0, 0);
        }
    }

    // ---- bias + relu -> hs (C/D: row = q*4+reg, col = lane&15) ----
    #pragma unroll
    for (int b = 0; b < 4; ++b) {
        #pragma unroll
        for (int i = 0; i < 4; ++i) {
            int row = wv * 16 + q * 4 + i;
            int col = 16 * b + m;
            hs[row * HSW + col] = fmaxf(acc[b][i] + b1v[b], 0.0f);
        }
    }
    __syncthreads();

    // ---- GEMM2 + tanh: 256 threads = 64 rows x 4 outputs ----
    {
        int r = tid & 63, qi = tid >> 6;       // qi wave-uniform -> W2/b2 scalar loads
        float s = b2[qi];
        #pragma unroll 8
        for (int k = 0; k < 64; ++k)
            s = fmaf(hs[r * HSW + k], W2[qi * 64 + k], s);   // (r+k)%32: 2-way, free
        angs[r * 4 + qi] = tanhf(s);
    }
    __syncthreads();

    // ---- quantum circuit: one thread per row (wave 0) ----
    if (tid < 64) {
        float ca[4], sa[4];
        #pragma unroll
        for (int i = 0; i < 4; ++i)
            __sincosf(0.5f * angs[tid * 4 + i], &sa[i], &ca[i]);

        // state idx = w0*8 + w1*4 + w2*2 + w3
        float re[16], im[16];
        #pragma unroll
        for (int idx = 0; idx < 16; ++idx) {
            re[idx] = (idx & 8 ? sa[0] : ca[0]) * (idx & 4 ? sa[1] : ca[1]) *
                      (idx & 2 ? sa[2] : ca[2]) * (idx & 1 ? sa[3] : ca[3]);
            im[idx] = 0.0f;
        }
        #pragma unroll
        for (int l = 0; l < 2; ++l) {
            #pragma unroll
            for (int i = 0; i < 4; ++i) {
                const float cy = trig[(l * 4 + i) * 4 + 0];
                const float sy = trig[(l * 4 + i) * 4 + 1];
                const float cz = trig[(l * 4 + i) * 4 + 2];
                const float sz = trig[(l * 4 + i) * 4 + 3];
                const int mq = 8 >> i;
                #pragma unroll
                for (int idx = 0; idx < 16; ++idx) {
                    if (!(idx & mq)) {
                        int j = idx | mq;
                        float ar = re[idx], ai = im[idx], br = re[j], bi = im[j];
                        re[idx] = fmaf(cy, ar, -sy * br);
                        im[idx] = fmaf(cy, ai, -sy * bi);
                        re[j]   = fmaf(sy, ar,  cy * br);
                        im[j]   = fmaf(sy, ai,  cy * bi);
                    }
                }
                #pragma unroll
                for (int idx = 0; idx < 16; ++idx) {
                    float sgn = (idx & mq) ? sz : -sz;
                    float ar = re[idx], ai = im[idx];
                    re[idx] = fmaf(ar, cz, -ai * sgn);
                    im[idx] = fmaf(ar, sgn, ai * cz);
                }
            }
            #pragma unroll
            for (int c = 0; c < 4; ++c) {
                int t  = (c + 1) & 3;
                int mc = 8 >> c, mt = 8 >> t;
                #pragma unroll
                for (int idx = 0; idx < 16; ++idx) {
                    if ((idx & mc) && !(idx & mt)) {
                        int j = idx | mt;
                        float tr = re[idx]; re[idx] = re[j]; re[j] = tr;
                        float ti = im[idx]; im[idx] = im[j]; im[j] = ti;
                    }
                }
            }
        }
        float z = 0.0f;
        #pragma unroll
        for (int idx = 0; idx < 16; ++idx) {
            float p = re[idx] * re[idx] + im[idx] * im[idx];
            z += (idx & 8) ? -p : p;
        }
        out[row0 + tid] = z;
    }
}

extern "C" void kernel_launch(void* const* d_in, const int* in_sizes, int n_in,
                              void* d_out, int out_size, void* d_ws, size_t ws_size,
                              hipStream_t stream) {
    const float* x  = (const float*)d_in[0];
    const float* W1 = (const float*)d_in[1];
    const float* b1 = (const float*)d_in[2];
    const float* W2 = (const float*)d_in[3];
    const float* b2 = (const float*)d_in[4];
    const float* qw = (const float*)d_in[5];
    float* out = (float*)d_out;
    _Float16* w1h = (_Float16*)d_ws;     // 32 KB scratch

    w1_cvt<<<16, 256, 0, stream>>>(W1, w1h);
    const int B = in_sizes[0] / KDIM;    // 65536
    qc_fused<<<B / BM, 256, 0, stream>>>(x, w1h, b1, W2, b2, qw, out);
}

// Round 5
// 106.871 us; speedup vs baseline: 1.1033x; 1.1033x over previous
//
#include <hip/hip_runtime.h>
#include <math.h>

typedef _Float16 half8   __attribute__((ext_vector_type(8)));
typedef _Float16 half4v  __attribute__((ext_vector_type(4)));
typedef float    float4v __attribute__((ext_vector_type(4)));

#define BM    128
#define KDIM  256
#define WSTR  264   // halves per W1-LDS row (256 + 8 pad) -> B-frag b128 reads, 8-group banks
#define HTS   132   // hs_t stride (floats): hs_t[col][row], 128 rows + 4 pad

__global__ __launch_bounds__(256, 2)
void qc_fused(const float* __restrict__ x,
              const float* __restrict__ W1,
              const float* __restrict__ b1,
              const float* __restrict__ W2,
              const float* __restrict__ b2,
              const float* __restrict__ qw,
              float* __restrict__ out)
{
    // whs (fp16 W1, 64x264 = 33792 B) reused as hs_t (fp32, 64 cols x 132 = 33792 B)
    __shared__ __align__(16) unsigned char smem_raw[64 * WSTR * 2];
    __shared__ float angs[BM * 4];
    __shared__ float trig[32];        // [layer][qubit][{cy,sy,cz,sz}]

    _Float16* whs = (_Float16*)smem_raw;
    float*    hst = (float*)smem_raw;

    const int tid  = threadIdx.x;
    const int lane = tid & 63;
    const int wv   = tid >> 6;        // wave -> rows wv*32 .. wv*32+31
    const int m    = lane & 15;
    const int q    = lane >> 4;
    const int row0 = blockIdx.x * BM;

    if (tid < 8) {
        int l = tid >> 2, i = tid & 3;
        float wy = qw[(l * 4 + i) * 2 + 0];
        float wz = qw[(l * 4 + i) * 2 + 1];
        float sy, cy, sz, cz;
        sincosf(0.5f * wy, &sy, &cy);
        sincosf(0.5f * wz, &sz, &cz);
        trig[(l * 4 + i) * 4 + 0] = cy;
        trig[(l * 4 + i) * 4 + 1] = sy;
        trig[(l * 4 + i) * 4 + 2] = cz;
        trig[(l * 4 + i) * 4 + 3] = sz;
    }

    // ---- x: ALL 32 dwordx4 loads issued first (deepest HBM queue) ----
    // A-frag layout A[m][k=q*8+j]; row-set a covers rows wv*32 + a*16 + m
    const float* xr0 = x + (size_t)(row0 + wv * 32 +      m) * KDIM + q * 8;
    const float* xr1 = x + (size_t)(row0 + wv * 32 + 16 + m) * KDIM + q * 8;
    float4v xv0[16], xv1[16];
    #pragma unroll
    for (int f = 0; f < 8; ++f) {
        xv0[2 * f]     = *(const float4v*)(xr0 + f * 32);
        xv0[2 * f + 1] = *(const float4v*)(xr0 + f * 32 + 4);
        xv1[2 * f]     = *(const float4v*)(xr1 + f * 32);
        xv1[2 * f + 1] = *(const float4v*)(xr1 + f * 32 + 4);
    }

    // b1 per-lane for epilogue (tiny, L2-hit)
    float b1v[4];
    #pragma unroll
    for (int b = 0; b < 4; ++b) b1v[b] = b1[16 * b + m];

    // ---- stage W1 (64x256) fp32 -> fp16 into LDS (queued behind x) ----
    {
        const int rw = tid >> 2;            // 0..63
        const int c0 = (tid & 3) * 4;       // 0,4,8,12
        const float* wrow = W1 + (size_t)rw * KDIM;
        #pragma unroll
        for (int j = 0; j < 16; ++j) {
            float4v v = *(const float4v*)(wrow + c0 + 16 * j);
            half4v h;
            h[0] = (_Float16)v[0]; h[1] = (_Float16)v[1];
            h[2] = (_Float16)v[2]; h[3] = (_Float16)v[3];
            *(half4v*)&whs[rw * WSTR + c0 + 16 * j] = h;   // 2-way banks: free
        }
    }

    // ---- cvt x -> fp16 A-frags ----
    half8 af0[8], af1[8];
    #pragma unroll
    for (int f = 0; f < 8; ++f) {
        #pragma unroll
        for (int j = 0; j < 4; ++j) {
            af0[f][j]     = (_Float16)xv0[2 * f][j];
            af0[f][4 + j] = (_Float16)xv0[2 * f + 1][j];
            af1[f][j]     = (_Float16)xv1[2 * f][j];
            af1[f][4 + j] = (_Float16)xv1[2 * f + 1][j];
        }
    }

    __syncthreads();

    // ---- MFMA: wave tile 32 rows x 64 cols, K=256 in 8 steps ----
    float4v acc[2][4] = {};
    #pragma unroll
    for (int f = 0; f < 8; ++f) {
        const int ko = f * 32 + q * 8;
        #pragma unroll
        for (int b = 0; b < 4; ++b) {
            half8 bf = *(const half8*)&whs[(16 * b + m) * WSTR + ko];
            acc[0][b] = __builtin_amdgcn_mfma_f32_16x16x32_f16(af0[f], bf, acc[0][b], 0, 0, 0);
            acc[1][b] = __builtin_amdgcn_mfma_f32_16x16x32_f16(af1[f], bf, acc[1][b], 0, 0, 0);
        }
    }
    __syncthreads();   // all B-frag reads done before hs_t overwrites whs

    // ---- bias + relu -> hs_t[col][row], b128 stores (4 consecutive rows) ----
    #pragma unroll
    for (int a = 0; a < 2; ++a) {
        #pragma unroll
        for (int b = 0; b < 4; ++b) {
            int row = wv * 32 + a * 16 + q * 4;   // C/D: row = q*4 + i
            int col = 16 * b + m;                 //      col = m
            float4v v;
            #pragma unroll
            for (int i = 0; i < 4; ++i) v[i] = fmaxf(acc[a][b][i] + b1v[b], 0.0f);
            *(float4v*)&hst[col * HTS + row] = v;
        }
    }
    __syncthreads();

    // ---- GEMM2 + tanh: 256 threads = 128 rows x 2 outputs each ----
    {
        int r = tid & 127, pair = tid >> 7;        // wave-uniform pair -> scalar W2/b2
        float s0 = b2[2 * pair], s1 = b2[2 * pair + 1];
        const float* w2a = W2 + (2 * pair) * 64;
        const float* w2b = W2 + (2 * pair + 1) * 64;
        #pragma unroll 8
        for (int k = 0; k < 64; ++k) {
            float hv = hst[k * HTS + r];           // lanes consecutive: 2-way, free
            s0 = fmaf(hv, w2a[k], s0);
            s1 = fmaf(hv, w2b[k], s1);
        }
        angs[r * 4 + 2 * pair]     = tanhf(s0);
        angs[r * 4 + 2 * pair + 1] = tanhf(s1);
    }
    __syncthreads();

    // ---- quantum circuit: one thread per row (waves 0-1) ----
    if (tid < BM) {
        float ca[4], sa[4];
        #pragma unroll
        for (int i = 0; i < 4; ++i)
            __sincosf(0.5f * angs[tid * 4 + i], &sa[i], &ca[i]);

        // state idx = w0*8 + w1*4 + w2*2 + w3
        float re[16], im[16];
        #pragma unroll
        for (int idx = 0; idx < 16; ++idx) {
            re[idx] = (idx & 8 ? sa[0] : ca[0]) * (idx & 4 ? sa[1] : ca[1]) *
                      (idx & 2 ? sa[2] : ca[2]) * (idx & 1 ? sa[3] : ca[3]);
            im[idx] = 0.0f;
        }
        #pragma unroll
        for (int l = 0; l < 2; ++l) {
            #pragma unroll
            for (int i = 0; i < 4; ++i) {
                const float cy = trig[(l * 4 + i) * 4 + 0];
                const float sy = trig[(l * 4 + i) * 4 + 1];
                const float cz = trig[(l * 4 + i) * 4 + 2];
                const float sz = trig[(l * 4 + i) * 4 + 3];
                const int mq = 8 >> i;
                #pragma unroll
                for (int idx = 0; idx < 16; ++idx) {
                    if (!(idx & mq)) {
                        int j = idx | mq;
                        float ar = re[idx], ai = im[idx], br = re[j], bi = im[j];
                        re[idx] = fmaf(cy, ar, -sy * br);
                        im[idx] = fmaf(cy, ai, -sy * bi);
                        re[j]   = fmaf(sy, ar,  cy * br);
                        im[j]   = fmaf(sy, ai,  cy * bi);
                    }
                }
                #pragma unroll
                for (int idx = 0; idx < 16; ++idx) {
                    float sgn = (idx & mq) ? sz : -sz;
                    float ar = re[idx], ai = im[idx];
                    re[idx] = fmaf(ar, cz, -ai * sgn);
                    im[idx] = fmaf(ar, sgn, ai * cz);
                }
            }
            #pragma unroll
            for (int c = 0; c < 4; ++c) {
                int t  = (c + 1) & 3;
                int mc = 8 >> c, mt = 8 >> t;
                #pragma unroll
                for (int idx = 0; idx < 16; ++idx) {
                    if ((idx & mc) && !(idx & mt)) {
                        int j = idx | mt;
                        float tr = re[idx]; re[idx] = re[j]; re[j] = tr;
                        float ti = im[idx]; im[idx] = im[j]; im[j] = ti;
                    }
                }
            }
        }
        float z = 0.0f;
        #pragma unroll
        for (int idx = 0; idx < 16; ++idx) {
            float p = re[idx] * re[idx] + im[idx] * im[idx];
            z += (idx & 8) ? -p : p;
        }
        out[row0 + tid] = z;
    }
}

extern "C" void kernel_launch(void* const* d_in, const int* in_sizes, int n_in,
                              void* d_out, int out_size, void* d_ws, size_t ws_size,
                              hipStream_t stream) {
    const float* x  = (const float*)d_in[0];
    const float* W1 = (const float*)d_in[1];
    const float* b1 = (const float*)d_in[2];
    const float* W2 = (const float*)d_in[3];
    const float* b2 = (const float*)d_in[4];
    const float* qw = (const float*)d_in[5];
    float* out = (float*)d_out;
    const int B = in_sizes[0] / KDIM;    // 65536
    qc_fused<<<B / BM, 256, 0, stream>>>(x, W1, b1, W2, b2, qw, out);
}

// Round 6
// 105.144 us; speedup vs baseline: 1.1214x; 1.0164x over previous
//
#include <hip/hip_runtime.h>
#include <math.h>

typedef _Float16 half8   __attribute__((ext_vector_type(8)));
typedef _Float16 half4v  __attribute__((ext_vector_type(4)));
typedef float    float4v __attribute__((ext_vector_type(4)));

#define BM    64
#define KDIM  256
#define WSTR  264   // halves per W1-LDS row (256+8 pad); b128 B-frag reads = 2-way (free)
#define HSW   65    // fp32 h-tile stride: (r+k)%32 -> 2-way (free) on GEMM2 reads

__global__ __launch_bounds__(256, 4)
void qc_fused(const float* __restrict__ x,
              const float* __restrict__ W1,
              const float* __restrict__ b1,
              const float* __restrict__ W2,
              const float* __restrict__ b2,
              const float* __restrict__ qw,
              float* __restrict__ out)
{
    // whs (fp16 W1, 64x264 = 33792 B) reused as hs (fp32 64x65 = 16640 B) after MFMA
    __shared__ __align__(16) unsigned char smem_raw[64 * WSTR * 2];
    __shared__ float angs[BM * 4];
    __shared__ float trig[32];        // [layer][qubit][{cy,sy,cz,sz}]

    _Float16* whs = (_Float16*)smem_raw;
    float*    hs  = (float*)smem_raw;

    const int tid  = threadIdx.x;
    const int lane = tid & 63;
    const int wv   = tid >> 6;        // wave -> rows wv*16 .. wv*16+15
    const int m    = lane & 15;
    const int q    = lane >> 4;
    const int row0 = blockIdx.x * BM;

    if (tid < 8) {
        int l = tid >> 2, i = tid & 3;
        float wy = qw[(l * 4 + i) * 2 + 0];
        float wz = qw[(l * 4 + i) * 2 + 1];
        float sy, cy, sz, cz;
        sincosf(0.5f * wy, &sy, &cy);
        sincosf(0.5f * wz, &sz, &cz);
        trig[(l * 4 + i) * 4 + 0] = cy;
        trig[(l * 4 + i) * 4 + 1] = sy;
        trig[(l * 4 + i) * 4 + 2] = cz;
        trig[(l * 4 + i) * 4 + 3] = sz;
    }

    // A-frag layout: A[m][k = q*8 + j]; frag f covers k = f*32 + q*8 .. +7
    const float* xrow = x + (size_t)(row0 + wv * 16 + m) * KDIM + q * 8;

    // ---- chunk 0 x-loads (f=0..3): 8 float4 = 32 VGPR live ----
    float4v xv[8];
    #pragma unroll
    for (int f = 0; f < 4; ++f) {
        xv[2 * f]     = *(const float4v*)(xrow + f * 32);
        xv[2 * f + 1] = *(const float4v*)(xrow + f * 32 + 4);
    }

    // b1 per-lane for epilogue (tiny, L2-hit)
    float b1v[4];
    #pragma unroll
    for (int b = 0; b < 4; ++b) b1v[b] = b1[16 * b + m];

    // ---- stage W1 (64x256) fp32 -> fp16 into LDS, fully coalesced ----
    // flat i = j*1024 + tid*4  ->  row = 4j + wv, col = lane*4
    {
        const float* wsrc = W1 + tid * 4;
        _Float16*    wdst = &whs[wv * WSTR + lane * 4];
        #pragma unroll 4
        for (int j = 0; j < 16; ++j) {
            float4v v = *(const float4v*)(wsrc + j * 1024);
            half4v h;
            h[0] = (_Float16)v[0]; h[1] = (_Float16)v[1];
            h[2] = (_Float16)v[2]; h[3] = (_Float16)v[3];
            *(half4v*)(wdst + j * 4 * WSTR) = h;   // 2-way banks: free
        }
    }

    // ---- cvt chunk 0 -> af[0..3], freeing xv; then issue chunk 1 loads ----
    half8 af[8];
    #pragma unroll
    for (int f = 0; f < 4; ++f) {
        #pragma unroll
        for (int j = 0; j < 4; ++j) {
            af[f][j]     = (_Float16)xv[2 * f][j];
            af[f][4 + j] = (_Float16)xv[2 * f + 1][j];
        }
    }
    #pragma unroll
    for (int f = 4; f < 8; ++f) {
        xv[2 * (f - 4)]     = *(const float4v*)(xrow + f * 32);
        xv[2 * (f - 4) + 1] = *(const float4v*)(xrow + f * 32 + 4);
    }

    __syncthreads();   // W1 staged

    // ---- MFMA chunk 0 (overlaps chunk-1 loads in flight) ----
    float4v acc[4] = {};
    #pragma unroll
    for (int f = 0; f < 4; ++f) {
        const int ko = f * 32 + q * 8;
        #pragma unroll
        for (int b = 0; b < 4; ++b) {
            half8 bf = *(const half8*)&whs[(16 * b + m) * WSTR + ko];
            acc[b] = __builtin_amdgcn_mfma_f32_16x16x32_f16(af[f], bf, acc[b], 0, 0, 0);
        }
    }
    // ---- cvt chunk 1, MFMA chunk 1 ----
    #pragma unroll
    for (int f = 4; f < 8; ++f) {
        #pragma unroll
        for (int j = 0; j < 4; ++j) {
            af[f][j]     = (_Float16)xv[2 * (f - 4)][j];
            af[f][4 + j] = (_Float16)xv[2 * (f - 4) + 1][j];
        }
    }
    #pragma unroll
    for (int f = 4; f < 8; ++f) {
        const int ko = f * 32 + q * 8;
        #pragma unroll
        for (int b = 0; b < 4; ++b) {
            half8 bf = *(const half8*)&whs[(16 * b + m) * WSTR + ko];
            acc[b] = __builtin_amdgcn_mfma_f32_16x16x32_f16(af[f], bf, acc[b], 0, 0, 0);
        }
    }
    __syncthreads();   // all B-frag reads done before hs overwrites whs

    // ---- bias + relu -> hs (C/D: row = q*4+reg, col = lane&15) ----
    #pragma unroll
    for (int b = 0; b < 4; ++b) {
        #pragma unroll
        for (int i = 0; i < 4; ++i) {
            int row = wv * 16 + q * 4 + i;
            int col = 16 * b + m;
            hs[row * HSW + col] = fmaxf(acc[b][i] + b1v[b], 0.0f);
        }
    }
    __syncthreads();

    // ---- GEMM2 + tanh: 256 threads = 64 rows x 4 outputs ----
    {
        int r = tid & 63, qi = tid >> 6;       // qi wave-uniform -> W2/b2 scalar loads
        float s = b2[qi];
        #pragma unroll 8
        for (int k = 0; k < 64; ++k)
            s = fmaf(hs[r * HSW + k], W2[qi * 64 + k], s);   // (r+k)%32: 2-way, free
        angs[r * 4 + qi] = tanhf(s);
    }
    __syncthreads();

    // ---- quantum circuit: one thread per row (wave 0) ----
    if (tid < 64) {
        float ca[4], sa[4];
        #pragma unroll
        for (int i = 0; i < 4; ++i)
            __sincosf(0.5f * angs[tid * 4 + i], &sa[i], &ca[i]);

        // state idx = w0*8 + w1*4 + w2*2 + w3
        float re[16], im[16];
        #pragma unroll
        for (int idx = 0; idx < 16; ++idx) {
            re[idx] = (idx & 8 ? sa[0] : ca[0]) * (idx & 4 ? sa[1] : ca[1]) *
                      (idx & 2 ? sa[2] : ca[2]) * (idx & 1 ? sa[3] : ca[3]);
            im[idx] = 0.0f;
        }
        #pragma unroll
        for (int l = 0; l < 2; ++l) {
            #pragma unroll
            for (int i = 0; i < 4; ++i) {
                const float cy = trig[(l * 4 + i) * 4 + 0];
                const float sy = trig[(l * 4 + i) * 4 + 1];
                const float cz = trig[(l * 4 + i) * 4 + 2];
                const float sz = trig[(l * 4 + i) * 4 + 3];
                const int mq = 8 >> i;
                #pragma unroll
                for (int idx = 0; idx < 16; ++idx) {
                    if (!(idx & mq)) {
                        int j = idx | mq;
                        float ar = re[idx], ai = im[idx], br = re[j], bi = im[j];
                        re[idx] = fmaf(cy, ar, -sy * br);
                        im[idx] = fmaf(cy, ai, -sy * bi);
                        re[j]   = fmaf(sy, ar,  cy * br);
                        im[j]   = fmaf(sy, ai,  cy * bi);
                    }
                }
                #pragma unroll
                for (int idx = 0; idx < 16; ++idx) {
                    float sgn = (idx & mq) ? sz : -sz;
                    float ar = re[idx], ai = im[idx];
                    re[idx] = fmaf(ar, cz, -ai * sgn);
                    im[idx] = fmaf(ar, sgn, ai * cz);
                }
            }
            #pragma unroll
            for (int c = 0; c < 4; ++c) {
                int t  = (c + 1) & 3;
                int mc = 8 >> c, mt = 8 >> t;
                #pragma unroll
                for (int idx = 0; idx < 16; ++idx) {
                    if ((idx & mc) && !(idx & mt)) {
                        int j = idx | mt;
                        float tr = re[idx]; re[idx] = re[j]; re[j] = tr;
                        float ti = im[idx]; im[idx] = im[j]; im[j] = ti;
                    }
                }
            }
        }
        float z = 0.0f;
        #pragma unroll
        for (int idx = 0; idx < 16; ++idx) {
            float p = re[idx] * re[idx] + im[idx] * im[idx];
            z += (idx & 8) ? -p : p;
        }
        out[row0 + tid] = z;
    }
}

extern "C" void kernel_launch(void* const* d_in, const int* in_sizes, int n_in,
                              void* d_out, int out_size, void* d_ws, size_t ws_size,
                              hipStream_t stream) {
    const float* x  = (const float*)d_in[0];
    const float* W1 = (const float*)d_in[1];
    const float* b1 = (const float*)d_in[2];
    const float* W2 = (const float*)d_in[3];
    const float* b2 = (const float*)d_in[4];
    const float* qw = (const float*)d_in[5];
    float* out = (float*)d_out;
    const int B = in_sizes[0] / KDIM;    // 65536
    qc_fused<<<B / BM, 256, 0, stream>>>(x, W1, b1, W2, b2, qw, out);
}